// Round 7
// baseline (21661.188 us; speedup 1.0000x reference)
//
#include <hip/hip_runtime.h>
#include <hip/hip_bf16.h>

#define S_ 1024
#define B_ 64
#define E_ 512
#define H_ 512
#define G3_ 1536

typedef __hip_bfloat16 bf16;
typedef unsigned long long ULL;

// ---------- dtype helpers ----------
template<typename T> struct alignas(4*sizeof(T)) V4 { T v[4]; };

__device__ __forceinline__ float toF(float x){ return x; }
__device__ __forceinline__ float toF(bf16 x){ return __bfloat162float(x); }
__device__ __forceinline__ void storeF(float* p, float v){ *p = v; }
__device__ __forceinline__ void storeF(bf16* p, float v){ *p = __float2bfloat16(v); }

// stamped 8B pair: low 32 = f32 value, high 32 = step stamp. One relaxed
// agent-scope atomic store publishes value+stamp together (L3-coherent).
__device__ __forceinline__ ULL cohLoad8(const ULL* p){
  return __hip_atomic_load(p, __ATOMIC_RELAXED, __HIP_MEMORY_SCOPE_AGENT);
}
__device__ __forceinline__ void pairStore(ULL* p, float v, unsigned stamp){
  const ULL u = ((ULL)stamp << 32) | (ULL)__float_as_uint(v);
  __hip_atomic_store(p, u, __ATOMIC_RELAXED, __HIP_MEMORY_SCOPE_AGENT);
}
__device__ __forceinline__ unsigned pairStamp(ULL v){ return (unsigned)(v >> 32); }
__device__ __forceinline__ float pairVal(ULL v){ return __uint_as_float((unsigned)v); }

// ------------------------------ signal kernel -------------------------------
__global__ __launch_bounds__(256)
void signal_kernel(float* __restrict__ out, long n, float v)
{
  long i = (long)blockIdx.x * 256 + threadIdx.x;
  const long stride = (long)gridDim.x * 256;
  for (; i < n; i += stride) out[i] = v;
}

// ------------------------------- tiled GEMM ---------------------------------
// C[m][n] = sum_k A[m][k] * W[n][k]
// AMODE 0: A[m][k] = emb[src[m]][k] * (src[m]!=0)            (fp32 gather)
// AMODE 1: A[m][k] = k<H ? Af[m*rsF+k] (HT) : Ab[m*rsB+k-H] (XT)
// EPI 0: store raw XT to Cx (row stride N). EPI 1: store f32 tanh(acc+bias).
template<typename XT, typename HT, int AMODE, int EPI>
__global__ __launch_bounds__(256, 2)
void gemm_tile(const int* __restrict__ src, const float* __restrict__ emb,
               const HT* __restrict__ Af, int rsF, const XT* __restrict__ Ab, int rsB,
               const float* __restrict__ W,
               XT* __restrict__ Cx, float* __restrict__ Cf, const float* __restrict__ bias,
               int N, int K)
{
  __shared__ float As[16][132];
  __shared__ float Bs[16][132];
  __shared__ int s_tok[128];
  const int m0 = blockIdx.x * 128;
  const int n0 = blockIdx.y * 128;
  const int tid = threadIdx.x;
  const int tx = tid & 15, ty = tid >> 4;

  if constexpr (AMODE == 0) {
    if (tid < 128) s_tok[tid] = src[m0 + tid];
  }
  __syncthreads();

  float acc[8][8];
  #pragma unroll
  for (int i = 0; i < 8; ++i)
    #pragma unroll
    for (int j = 0; j < 8; ++j) acc[i][j] = 0.f;

  for (int k0 = 0; k0 < K; k0 += 16) {
    #pragma unroll
    for (int i = 0; i < 2; ++i) {
      const int f = tid * 2 + i;
      const int r = f >> 2, kq = f & 3;
      const int kk = k0 + kq * 4;
      float a0, a1, a2, a3;
      if constexpr (AMODE == 0) {
        const int tok = s_tok[r];
        if (tok != 0) {
          float4 v = *(const float4*)(emb + (size_t)tok * E_ + kk);
          a0 = v.x; a1 = v.y; a2 = v.z; a3 = v.w;
        } else { a0 = a1 = a2 = a3 = 0.f; }
      } else {
        if (kk < H_) {
          V4<HT> v = *(const V4<HT>*)(Af + (size_t)(m0 + r) * rsF + kk);
          a0 = toF(v.v[0]); a1 = toF(v.v[1]); a2 = toF(v.v[2]); a3 = toF(v.v[3]);
        } else {
          V4<XT> v = *(const V4<XT>*)(Ab + (size_t)(m0 + r) * rsB + (kk - H_));
          a0 = toF(v.v[0]); a1 = toF(v.v[1]); a2 = toF(v.v[2]); a3 = toF(v.v[3]);
        }
      }
      As[kq*4+0][r] = a0; As[kq*4+1][r] = a1; As[kq*4+2][r] = a2; As[kq*4+3][r] = a3;
      float4 b = *(const float4*)(W + (size_t)(n0 + r) * K + kk);
      Bs[kq*4+0][r] = b.x; Bs[kq*4+1][r] = b.y; Bs[kq*4+2][r] = b.z; Bs[kq*4+3][r] = b.w;
    }
    __syncthreads();
    #pragma unroll
    for (int k = 0; k < 16; ++k) {
      float4 ra0 = *(const float4*)&As[k][ty*8];
      float4 ra1 = *(const float4*)&As[k][ty*8+4];
      float4 rb0 = *(const float4*)&Bs[k][tx*8];
      float4 rb1 = *(const float4*)&Bs[k][tx*8+4];
      float fa[8] = {ra0.x,ra0.y,ra0.z,ra0.w,ra1.x,ra1.y,ra1.z,ra1.w};
      float fb[8] = {rb0.x,rb0.y,rb0.z,rb0.w,rb1.x,rb1.y,rb1.z,rb1.w};
      #pragma unroll
      for (int i = 0; i < 8; ++i)
        #pragma unroll
        for (int j = 0; j < 8; ++j) acc[i][j] += fa[i] * fb[j];
    }
    __syncthreads();
  }

  if constexpr (EPI == 0) {
    #pragma unroll
    for (int i = 0; i < 8; ++i) {
      XT* crow = Cx + (size_t)(m0 + ty*8 + i) * N + n0 + tx*8;
      V4<XT> o0, o1;
      #pragma unroll
      for (int c = 0; c < 4; ++c) { storeF(&o0.v[c], acc[i][c]); storeF(&o1.v[c], acc[i][4+c]); }
      ((V4<XT>*)crow)[0] = o0; ((V4<XT>*)crow)[1] = o1;
    }
  } else {
    float bj[8];
    #pragma unroll
    for (int j = 0; j < 8; ++j) bj[j] = bias[n0 + tx*8 + j];
    #pragma unroll
    for (int i = 0; i < 8; ++i) {
      float* crow = Cf + (size_t)(m0 + ty*8 + i) * N + n0 + tx*8;
      float4 o0, o1;
      o0.x = tanhf(acc[i][0]+bj[0]); o0.y = tanhf(acc[i][1]+bj[1]);
      o0.z = tanhf(acc[i][2]+bj[2]); o0.w = tanhf(acc[i][3]+bj[3]);
      o1.x = tanhf(acc[i][4]+bj[4]); o1.y = tanhf(acc[i][5]+bj[5]);
      o1.z = tanhf(acc[i][6]+bj[6]); o1.w = tanhf(acc[i][7]+bj[7]);
      ((float4*)crow)[0] = o0; ((float4*)crow)[1] = o1;
    }
  }
}

// -------- in-place LayerNorm per 512-chunk (3 gates) + gain/bias fold -------
template<typename XT>
__global__ __launch_bounds__(256)
void ln3_kernel(XT* __restrict__ xp, const float* __restrict__ g,
                const float* __restrict__ be, const float* __restrict__ b)
{
  const size_t base = (size_t)blockIdx.x * G3_;
  const int t = threadIdx.x;
  float v[6];
  #pragma unroll
  for (int gg = 0; gg < 3; ++gg) {
    v[gg*2+0] = toF(xp[base + gg*512 + t]);
    v[gg*2+1] = toF(xp[base + gg*512 + 256 + t]);
  }
  float s0 = v[0]+v[1], q0 = v[0]*v[0]+v[1]*v[1];
  float s1 = v[2]+v[3], q1 = v[2]*v[2]+v[3]*v[3];
  float s2 = v[4]+v[5], q2 = v[4]*v[4]+v[5]*v[5];
  #pragma unroll
  for (int m = 1; m < 64; m <<= 1) {
    s0 += __shfl_xor(s0, m); q0 += __shfl_xor(q0, m);
    s1 += __shfl_xor(s1, m); q1 += __shfl_xor(q1, m);
    s2 += __shfl_xor(s2, m); q2 += __shfl_xor(q2, m);
  }
  __shared__ float red[4][6];
  __shared__ float stat[6];
  const int wid = t >> 6, lane = t & 63;
  if (lane == 0) { red[wid][0]=s0; red[wid][1]=q0; red[wid][2]=s1; red[wid][3]=q1; red[wid][4]=s2; red[wid][5]=q2; }
  __syncthreads();
  if (t < 6) stat[t] = red[0][t] + red[1][t] + red[2][t] + red[3][t];
  __syncthreads();
  #pragma unroll
  for (int gg = 0; gg < 3; ++gg) {
    const float mu  = stat[gg*2]   * (1.f/512.f);
    const float var = stat[gg*2+1] * (1.f/512.f) - mu*mu;
    const float sc  = rsqrtf(var + 1e-5f);
    #pragma unroll
    for (int u = 0; u < 2; ++u) {
      const int c = gg*512 + u*256 + t;
      storeF(&xp[base + c], (v[gg*2+u] - mu) * sc * g[c] + be[c] + b[c]);
    }
  }
}

// --------------------------- persistent scan kernel -------------------------
// Geometry: group = 8 batches; 8 groups/dir; 32 j-slice blocks per group.
// ALL cross-block exchange uses STAMPED 8B PAIRS (f32 value | u32 step stamp)
// written with one relaxed agent-scope atomic store: the stamp travels with
// the value, so there are no flags, no vmcnt drains, and each exchange costs
// a single L3 round-trip. Consumers poll the data itself (batched loads).
//   hS: [dir*64+b][512] stamped h state (stamp t+1 after step t; init 0)
//   pS: [group][48][32]  stamped LN partials (stamp t+1)
template<typename XT, typename HT>
__global__ __launch_bounds__(256, 2)
void scan_kernel(const XT* __restrict__ xp_f, const XT* __restrict__ xp_b,
                 const float* __restrict__ Whh_f, const float* __restrict__ Whh_b,
                 const float* __restrict__ gf, const float* __restrict__ bef, const float* __restrict__ bfv,
                 const float* __restrict__ gbv, const float* __restrict__ beb, const float* __restrict__ bbv,
                 ULL* __restrict__ hS, ULL* __restrict__ pS,
                 HT* __restrict__ houtF, int rsF, XT* __restrict__ houtB, int rsB,
                 float* __restrict__ outhid, int dirbase)
{
  __shared__ float hT[8][512];       // staged h for this batch-group
  __shared__ float red[4][16][26];   // cross-wave k-slice reduction
  __shared__ float sh[96];           // LN half-row sums
  __shared__ int sdead;

  const int bid  = blockIdx.x;
  const int gidx = dirbase*8 + (bid >> 5);   // global group 0..15
  const int dir  = gidx >> 3;
  const int bg   = gidx & 7;                 // batch group (8 batches)
  const int js   = bid & 31;                 // j slice
  const int tid  = threadIdx.x;
  const int jloc = tid & 15;
  const int pb   = tid >> 4;                 // dots: k-slice id; gates: b id
  const int wid  = tid >> 6;
  const int ksw  = (tid >> 4) & 3;
  const int j    = js*16 + jloc;

  const XT* xp   = dir ? xp_b : xp_f;
  const float* W = dir ? Whh_b : Whh_f;
  const float* gv  = dir ? gbv : gf;
  const float* bev = dir ? beb : bef;
  const float* bv  = dir ? bbv : bfv;
  ULL* pgrp = pS + (size_t)gidx * (48*32);

  if (tid == 0) sdead = 0;

  // W slice in registers; chunk order permuted by ksw (bank-conflict spread)
  float w[3][32];
  {
    #pragma unroll
    for (int r = 0; r < 3; ++r) {
      const float* wr = W + (size_t)(r*H_ + j) * H_ + pb * 32;
      #pragma unroll
      for (int c = 0; c < 8; ++c) {
        const int p = (c + ksw*2) & 7;
        float4 f = *(const float4*)(wr + p*4);
        w[r][c*4+0] = f.x; w[r][c*4+1] = f.y; w[r][c*4+2] = f.z; w[r][c*4+3] = f.w;
      }
    }
  }
  const float gr0 = gv[j],            gr1 = gv[H_+j],               gr2 = gv[2*H_+j];
  const float gb0 = bev[j] + bv[j],   gb1 = bev[H_+j] + bv[H_+j],   gb2 = bev[2*H_+j] + bv[2*H_+j];
  __syncthreads();   // sdead visible

  for (int t = 0; t < S_; ++t) {
    // prefetch xp gate inputs (independent of h -> overlaps the h poll)
    const int tf = dir ? (S_ - 1 - t) : t;
    float xr = 0.f, xz = 0.f, xn = 0.f;
    if (pb < 8) {
      const size_t xbase = ((size_t)tf * B_ + bg*8 + pb) * G3_;
      xr = toF(xp[xbase + j]);
      xz = toF(xp[xbase + H_ + j]);
      xn = toF(xp[xbase + 2*H_ + j]);
    }

    // ---- stage h(t-1): poll stamped slots directly (one L3 round-trip) ----
    {
      const int row = tid >> 5;          // 0..7
      const int seg = tid & 31;
      const ULL* hr = hS + (((size_t)(dir*B_ + bg*8 + row)) << 9);
      ULL v[16];
      if (!sdead) {
        int g = 0;
        for (;;) {
          #pragma unroll
          for (int i = 0; i < 16; ++i) v[i] = cohLoad8(hr + seg + i*32);
          bool all = true;
          #pragma unroll
          for (int i = 0; i < 16; ++i) all &= (pairStamp(v[i]) >= (unsigned)t);
          if (all) break;
          __builtin_amdgcn_s_sleep(1);
          if (++g > (1 << 16)) { sdead = 1; break; }
        }
      } else {
        #pragma unroll
        for (int i = 0; i < 16; ++i) v[i] = 0;
      }
      #pragma unroll
      for (int i = 0; i < 16; ++i) hT[row][seg + i*32] = pairVal(v[i]);
    }
    __syncthreads();

    // k-sliced dots for the 8 b of this group
    for (int b = 0; b < 8; ++b) {
      float a0 = 0.f, a1 = 0.f, a2 = 0.f;
      #pragma unroll
      for (int c = 0; c < 8; ++c) {
        const int p = (c + ksw*2) & 7;
        const float4 hv = *(const float4*)&hT[b][pb*32 + p*4];
        a0 += hv.x*w[0][c*4+0] + hv.y*w[0][c*4+1] + hv.z*w[0][c*4+2] + hv.w*w[0][c*4+3];
        a1 += hv.x*w[1][c*4+0] + hv.y*w[1][c*4+1] + hv.z*w[1][c*4+2] + hv.w*w[1][c*4+3];
        a2 += hv.x*w[2][c*4+0] + hv.y*w[2][c*4+1] + hv.z*w[2][c*4+2] + hv.w*w[2][c*4+3];
      }
      a0 += __shfl_xor(a0, 16); a0 += __shfl_xor(a0, 32);
      a1 += __shfl_xor(a1, 16); a1 += __shfl_xor(a1, 32);
      a2 += __shfl_xor(a2, 16); a2 += __shfl_xor(a2, 32);
      if (ksw == 0) {
        red[wid][jloc][b*3+0] = a0; red[wid][jloc][b*3+1] = a1; red[wid][jloc][b*3+2] = a2;
      }
    }
    __syncthreads();

    float vr = 0.f, vz = 0.f, vn = 0.f;
    if (pb < 8) {
      vr = red[0][jloc][pb*3+0]+red[1][jloc][pb*3+0]+red[2][jloc][pb*3+0]+red[3][jloc][pb*3+0];
      vz = red[0][jloc][pb*3+1]+red[1][jloc][pb*3+1]+red[2][jloc][pb*3+1]+red[3][jloc][pb*3+1];
      vn = red[0][jloc][pb*3+2]+red[1][jloc][pb*3+2]+red[2][jloc][pb*3+2]+red[3][jloc][pb*3+2];

      // LN-stat partials over this block's 16 j -> stamped group slots
      float sr = vr, qr = vr*vr, sz = vz, qz = vz*vz, sn = vn, qn = vn*vn;
      #pragma unroll
      for (int m = 1; m < 16; m <<= 1) {
        sr += __shfl_xor(sr, m); qr += __shfl_xor(qr, m);
        sz += __shfl_xor(sz, m); qz += __shfl_xor(qz, m);
        sn += __shfl_xor(sn, m); qn += __shfl_xor(qn, m);
      }
      if (jloc == 0) {
        const unsigned st = (unsigned)(t + 1);
        pairStore(&pgrp[(pb*6+0)*32 + js], sr, st);
        pairStore(&pgrp[(pb*6+1)*32 + js], qr, st);
        pairStore(&pgrp[(pb*6+2)*32 + js], sz, st);
        pairStore(&pgrp[(pb*6+3)*32 + js], qz, st);
        pairStore(&pgrp[(pb*6+4)*32 + js], sn, st);
        pairStore(&pgrp[(pb*6+5)*32 + js], qn, st);
      }
    }

    // ---- gather LN stats: poll the 32 stamped slots per half-row ----
    if (tid < 96 && !sdead) {
      const ULL* prow = pgrp + (tid >> 1) * 32 + (tid & 1) * 16;
      ULL v[16];
      int g = 0;
      for (;;) {
        #pragma unroll
        for (int i = 0; i < 16; ++i) v[i] = cohLoad8(prow + i);
        bool all = true;
        #pragma unroll
        for (int i = 0; i < 16; ++i) all &= (pairStamp(v[i]) >= (unsigned)(t + 1));
        if (all) break;
        __builtin_amdgcn_s_sleep(1);
        if (++g > (1 << 16)) { sdead = 1; break; }
      }
      float s = 0.f;
      #pragma unroll
      for (int i = 0; i < 16; ++i) s += pairVal(v[i]);
      sh[tid] = s;
    }
    __syncthreads();

    // gates + h update (thread owns (b=pb<8, j))
    if (pb < 8) {
      const int ab = bg*8 + pb;
      const float mur   = (sh[(pb*6+0)*2] + sh[(pb*6+0)*2+1]) * (1.f/512.f);
      const float qrr   = (sh[(pb*6+1)*2] + sh[(pb*6+1)*2+1]) * (1.f/512.f);
      const float muz   = (sh[(pb*6+2)*2] + sh[(pb*6+2)*2+1]) * (1.f/512.f);
      const float qzz   = (sh[(pb*6+3)*2] + sh[(pb*6+3)*2+1]) * (1.f/512.f);
      const float mun   = (sh[(pb*6+4)*2] + sh[(pb*6+4)*2+1]) * (1.f/512.f);
      const float qnn   = (sh[(pb*6+5)*2] + sh[(pb*6+5)*2+1]) * (1.f/512.f);
      const float hr_ = (vr - mur) * rsqrtf(qrr - mur*mur + 1e-5f) * gr0 + gb0;
      const float hz_ = (vz - muz) * rsqrtf(qzz - muz*muz + 1e-5f) * gr1 + gb1;
      const float hn_ = (vn - mun) * rsqrtf(qnn - mun*mun + 1e-5f) * gr2 + gb2;
      const float rg = 1.f / (1.f + __expf(-(xr + hr_)));
      const float zg = 1.f / (1.f + __expf(-(xz + hz_)));
      const float ng = tanhf(xn + rg * hn_);
      const float hprev = hT[pb][j];
      const float hnew = (1.f - zg) * ng + zg * hprev;
      pairStore(&hS[(((size_t)(dir*B_ + ab)) << 9) + j], hnew, (unsigned)(t + 1));
      if (dir == 0) storeF(&houtF[((size_t)tf * B_ + ab) * rsF + j], hnew);
      else          storeF(&houtB[((size_t)tf * B_ + ab) * rsB + j], hnew);
      if (t == S_ - 1) outhid[((size_t)dir * B_ + ab) * H_ + j] = hnew;
    }
    __syncthreads();   // protect hT/red/sh reuse next iteration
  }
}

// --------------------------------- host side --------------------------------
// ctrl: hS 2*64*512 ULL = 512KB | pS 16*48*32 ULL = 192KB  -> 720896 B
static const size_t kCtrlBytes = 720896;
static const size_t kXpElems = (size_t)S_ * B_ * G3_;   // 100,663,296
static const size_t kHElems  = (size_t)S_ * B_ * H_;    //  33,554,432

struct Args {
  const int* src; const float* emb;
  const float *Wih_f, *Whh_f, *bih_f, *bhh_f, *gih_f, *beih_f, *ghh_f, *behh_f;
  const float *Wih_b, *Whh_b, *bih_b, *bhh_b, *gih_b, *beih_b, *ghh_b, *behh_b;
  const float *Wout, *bout;
  float* out; void* ws; hipStream_t stream;
};

// parallel: both directions' xp live (XT); h-histories alias into xp cols 0..511
template<typename XT>
static void run_parallel(const Args& a)
{
  ULL* hS = (ULL*)a.ws;
  ULL* pS = hS + 65536;
  XT* xpf = (XT*)((char*)a.ws + kCtrlBytes);
  XT* xpb = xpf + kXpElems;
  float* outhid = a.out + kHElems;

  hipMemsetAsync(a.ws, 0, kCtrlBytes, a.stream);

  gemm_tile<XT,XT,0,0><<<dim3(512,12), dim3(256), 0, a.stream>>>(
      a.src, a.emb, (const XT*)nullptr, 0, (const XT*)nullptr, 0,
      a.Wih_f, xpf, nullptr, nullptr, G3_, E_);
  gemm_tile<XT,XT,0,0><<<dim3(512,12), dim3(256), 0, a.stream>>>(
      a.src, a.emb, (const XT*)nullptr, 0, (const XT*)nullptr, 0,
      a.Wih_b, xpb, nullptr, nullptr, G3_, E_);
  ln3_kernel<XT><<<dim3(S_*B_), dim3(256), 0, a.stream>>>(xpf, a.gih_f, a.beih_f, a.bih_f);
  ln3_kernel<XT><<<dim3(S_*B_), dim3(256), 0, a.stream>>>(xpb, a.gih_b, a.beih_b, a.bih_b);

  scan_kernel<XT,XT><<<dim3(512), dim3(256), 0, a.stream>>>(
      xpf, xpb, a.Whh_f, a.Whh_b, a.ghh_f, a.behh_f, a.bhh_f,
      a.ghh_b, a.behh_b, a.bhh_b, hS, pS,
      xpf, G3_, xpb, G3_, outhid, 0);

  gemm_tile<XT,XT,1,1><<<dim3(512,4), dim3(256), 0, a.stream>>>(
      nullptr, nullptr, xpf, G3_, xpb, G3_,
      a.Wout, (XT*)nullptr, a.out, a.bout, H_, 2*H_);
}

// sequential: one xp buffer (XT) reused; yf -> hf (HT), yb -> xp cols 0..511
template<typename XT, typename HT>
static void run_sequential(const Args& a)
{
  ULL* hS = (ULL*)a.ws;
  ULL* pS = hS + 65536;
  XT* xp = (XT*)((char*)a.ws + kCtrlBytes);
  HT* hf = (HT*)(xp + kXpElems);
  float* outhid = a.out + kHElems;

  hipMemsetAsync(a.ws, 0, kCtrlBytes, a.stream);

  gemm_tile<XT,XT,0,0><<<dim3(512,12), dim3(256), 0, a.stream>>>(
      a.src, a.emb, (const XT*)nullptr, 0, (const XT*)nullptr, 0,
      a.Wih_f, xp, nullptr, nullptr, G3_, E_);
  ln3_kernel<XT><<<dim3(S_*B_), dim3(256), 0, a.stream>>>(xp, a.gih_f, a.beih_f, a.bih_f);
  scan_kernel<XT,HT><<<dim3(256), dim3(256), 0, a.stream>>>(
      xp, xp, a.Whh_f, a.Whh_b, a.ghh_f, a.behh_f, a.bhh_f,
      a.ghh_b, a.behh_b, a.bhh_b, hS, pS,
      hf, H_, xp, G3_, outhid, 0);

  gemm_tile<XT,XT,0,0><<<dim3(512,12), dim3(256), 0, a.stream>>>(
      a.src, a.emb, (const XT*)nullptr, 0, (const XT*)nullptr, 0,
      a.Wih_b, xp, nullptr, nullptr, G3_, E_);
  ln3_kernel<XT><<<dim3(S_*B_), dim3(256), 0, a.stream>>>(xp, a.gih_b, a.beih_b, a.bih_b);
  scan_kernel<XT,HT><<<dim3(256), dim3(256), 0, a.stream>>>(
      xp, xp, a.Whh_f, a.Whh_b, a.ghh_f, a.behh_f, a.bhh_f,
      a.ghh_b, a.behh_b, a.bhh_b, hS, pS,
      hf, H_, xp, G3_, outhid, 1);

  gemm_tile<XT,HT,1,1><<<dim3(512,4), dim3(256), 0, a.stream>>>(
      nullptr, nullptr, hf, H_, xp, G3_,
      a.Wout, (XT*)nullptr, a.out, a.bout, H_, 2*H_);
}

extern "C" void kernel_launch(void* const* d_in, const int* in_sizes, int n_in,
                              void* d_out, int out_size, void* d_ws, size_t ws_size,
                              hipStream_t stream)
{
  Args a;
  a.src    = (const int*)  d_in[0];
  a.emb    = (const float*)d_in[1];
  a.Wih_f  = (const float*)d_in[2];
  a.Whh_f  = (const float*)d_in[3];
  a.bih_f  = (const float*)d_in[4];
  a.bhh_f  = (const float*)d_in[5];
  a.gih_f  = (const float*)d_in[6];
  a.beih_f = (const float*)d_in[7];
  a.ghh_f  = (const float*)d_in[8];
  a.behh_f = (const float*)d_in[9];
  a.Wih_b  = (const float*)d_in[10];
  a.Whh_b  = (const float*)d_in[11];
  a.bih_b  = (const float*)d_in[12];
  a.bhh_b  = (const float*)d_in[13];
  a.gih_b  = (const float*)d_in[14];
  a.beih_b = (const float*)d_in[15];
  a.ghh_b  = (const float*)d_in[16];
  a.behh_b = (const float*)d_in[17];
  a.Wout   = (const float*)d_in[18];
  a.bout   = (const float*)d_in[19];
  a.out = (float*)d_out;
  a.ws = d_ws;
  a.stream = stream;

  int dev = 0, cus = 0;
  hipGetDevice(&dev);
  hipDeviceGetAttribute(&cus, hipDeviceAttributeMultiprocessorCount, dev);

  const size_t needA = kCtrlBytes + kXpElems*4 + kHElems*2;  // ~470.5 MB fp32 xp, bf16 hf
  const size_t needB = kCtrlBytes + 2*kXpElems*2;            // ~403.4 MB bf16 parallel
  const size_t needC = kCtrlBytes + kXpElems*2 + kHElems*4;  // ~336.3 MB bf16 xp, fp32 hf
  const size_t needD = kCtrlBytes + kXpElems*2 + kHElems*2;  // ~269.2 MB bf16 all

  const bool sane = (n_in == 20) && (in_sizes[0] == S_*B_) && (in_sizes[1] == 32000*E_)
                 && (in_sizes[3] == G3_*H_) && (in_sizes[18] == H_*2*H_);

  float sigv = 0.f;
  bool ran = false;
  if (!sane) {
    sigv = 20000.f + (float)n_in;
  } else if (cus < 256) {
    sigv = 100000.f + (float)cus;
  } else if (ws_size >= needA) { run_sequential<float, bf16>(a); ran = true; }
  else if (ws_size >= needB) { run_parallel<bf16>(a);            ran = true; }
  else if (ws_size >= needC) { run_sequential<bf16, float>(a);   ran = true; }
  else if (ws_size >= needD) { run_sequential<bf16, bf16>(a);    ran = true; }
  else {
    unsigned wsMB = (unsigned)(ws_size >> 20);
    if (wsMB > 998) wsMB = 998;
    sigv = 1000.f + (float)wsMB;
  }

  if (!ran) {
    signal_kernel<<<dim3(1024), dim3(256), 0, stream>>>(a.out, (long)out_size, sigv);
  } else {
    hipError_t e = hipGetLastError();
    if (e != hipSuccess) {
      signal_kernel<<<dim3(1024), dim3(256), 0, stream>>>(a.out, (long)out_size,
                                                          10000.f + (float)(int)e);
    }
  }
}

// Round 8
// 13335.985 us; speedup vs baseline: 1.6243x; 1.6243x over previous
//
#include <hip/hip_runtime.h>
#include <hip/hip_bf16.h>
#include <hip/hip_fp16.h>

#define S_ 1024
#define B_ 64
#define E_ 512
#define H_ 512
#define G3_ 1536

typedef __hip_bfloat16 bf16;
typedef __half f16;
typedef unsigned long long ULL;

// ---------- dtype helpers ----------
template<typename T> struct alignas(4*sizeof(T)) V4 { T v[4]; };

__device__ __forceinline__ float toF(float x){ return x; }
__device__ __forceinline__ float toF(bf16 x){ return __bfloat162float(x); }
__device__ __forceinline__ float toF(f16 x){ return __half2float(x); }
__device__ __forceinline__ void storeF(float* p, float v){ *p = v; }
__device__ __forceinline__ void storeF(bf16* p, float v){ *p = __float2bfloat16(v); }
__device__ __forceinline__ void storeF(f16* p, float v){ *p = __float2half(v); }

__device__ __forceinline__ ULL cohLoad8(const ULL* p){
  return __hip_atomic_load(p, __ATOMIC_RELAXED, __HIP_MEMORY_SCOPE_AGENT);
}
__device__ __forceinline__ void cohStore4(float* p, float v){
  __hip_atomic_store(p, v, __ATOMIC_RELAXED, __HIP_MEMORY_SCOPE_AGENT);
}
__device__ __forceinline__ unsigned flagLoad(const unsigned* p){
  return __hip_atomic_load(p, __ATOMIC_RELAXED, __HIP_MEMORY_SCOPE_AGENT);
}
__device__ __forceinline__ void flagStore(unsigned* p, unsigned v){
  __hip_atomic_store(p, v, __ATOMIC_RELAXED, __HIP_MEMORY_SCOPE_AGENT);
}

// ------------------------------ signal kernel -------------------------------
__global__ __launch_bounds__(256)
void signal_kernel(float* __restrict__ out, long n, float v)
{
  long i = (long)blockIdx.x * 256 + threadIdx.x;
  const long stride = (long)gridDim.x * 256;
  for (; i < n; i += stride) out[i] = v;
}

// ------------------------------- tiled GEMM ---------------------------------
// C[m][n] = sum_k A[m][k] * W[n][k]
// AMODE 0: A[m][k] = emb[src[m]][k] * (src[m]!=0)            (fp32 gather)
// AMODE 1: A[m][k] = k<H ? Af[m*rsF+k] (HT) : Ab[m*rsB+k-H] (XT)
// EPI 0: store raw XT to Cx (row stride N). EPI 1: store f32 tanh(acc+bias).
template<typename XT, typename HT, int AMODE, int EPI>
__global__ __launch_bounds__(256, 2)
void gemm_tile(const int* __restrict__ src, const float* __restrict__ emb,
               const HT* __restrict__ Af, int rsF, const XT* __restrict__ Ab, int rsB,
               const float* __restrict__ W,
               XT* __restrict__ Cx, float* __restrict__ Cf, const float* __restrict__ bias,
               int N, int K)
{
  __shared__ float As[16][132];
  __shared__ float Bs[16][132];
  __shared__ int s_tok[128];
  const int m0 = blockIdx.x * 128;
  const int n0 = blockIdx.y * 128;
  const int tid = threadIdx.x;
  const int tx = tid & 15, ty = tid >> 4;

  if constexpr (AMODE == 0) {
    if (tid < 128) s_tok[tid] = src[m0 + tid];
  }
  __syncthreads();

  float acc[8][8];
  #pragma unroll
  for (int i = 0; i < 8; ++i)
    #pragma unroll
    for (int j = 0; j < 8; ++j) acc[i][j] = 0.f;

  for (int k0 = 0; k0 < K; k0 += 16) {
    #pragma unroll
    for (int i = 0; i < 2; ++i) {
      const int f = tid * 2 + i;
      const int r = f >> 2, kq = f & 3;
      const int kk = k0 + kq * 4;
      float a0, a1, a2, a3;
      if constexpr (AMODE == 0) {
        const int tok = s_tok[r];
        if (tok != 0) {
          float4 v = *(const float4*)(emb + (size_t)tok * E_ + kk);
          a0 = v.x; a1 = v.y; a2 = v.z; a3 = v.w;
        } else { a0 = a1 = a2 = a3 = 0.f; }
      } else {
        if (kk < H_) {
          V4<HT> v = *(const V4<HT>*)(Af + (size_t)(m0 + r) * rsF + kk);
          a0 = toF(v.v[0]); a1 = toF(v.v[1]); a2 = toF(v.v[2]); a3 = toF(v.v[3]);
        } else {
          V4<XT> v = *(const V4<XT>*)(Ab + (size_t)(m0 + r) * rsB + (kk - H_));
          a0 = toF(v.v[0]); a1 = toF(v.v[1]); a2 = toF(v.v[2]); a3 = toF(v.v[3]);
        }
      }
      As[kq*4+0][r] = a0; As[kq*4+1][r] = a1; As[kq*4+2][r] = a2; As[kq*4+3][r] = a3;
      float4 b = *(const float4*)(W + (size_t)(n0 + r) * K + kk);
      Bs[kq*4+0][r] = b.x; Bs[kq*4+1][r] = b.y; Bs[kq*4+2][r] = b.z; Bs[kq*4+3][r] = b.w;
    }
    __syncthreads();
    #pragma unroll
    for (int k = 0; k < 16; ++k) {
      float4 ra0 = *(const float4*)&As[k][ty*8];
      float4 ra1 = *(const float4*)&As[k][ty*8+4];
      float4 rb0 = *(const float4*)&Bs[k][tx*8];
      float4 rb1 = *(const float4*)&Bs[k][tx*8+4];
      float fa[8] = {ra0.x,ra0.y,ra0.z,ra0.w,ra1.x,ra1.y,ra1.z,ra1.w};
      float fb[8] = {rb0.x,rb0.y,rb0.z,rb0.w,rb1.x,rb1.y,rb1.z,rb1.w};
      #pragma unroll
      for (int i = 0; i < 8; ++i)
        #pragma unroll
        for (int j = 0; j < 8; ++j) acc[i][j] += fa[i] * fb[j];
    }
    __syncthreads();
  }

  if constexpr (EPI == 0) {
    #pragma unroll
    for (int i = 0; i < 8; ++i) {
      XT* crow = Cx + (size_t)(m0 + ty*8 + i) * N + n0 + tx*8;
      V4<XT> o0, o1;
      #pragma unroll
      for (int c = 0; c < 4; ++c) { storeF(&o0.v[c], acc[i][c]); storeF(&o1.v[c], acc[i][4+c]); }
      ((V4<XT>*)crow)[0] = o0; ((V4<XT>*)crow)[1] = o1;
    }
  } else {
    float bj[8];
    #pragma unroll
    for (int j = 0; j < 8; ++j) bj[j] = bias[n0 + tx*8 + j];
    #pragma unroll
    for (int i = 0; i < 8; ++i) {
      float* crow = Cf + (size_t)(m0 + ty*8 + i) * N + n0 + tx*8;
      float4 o0, o1;
      o0.x = tanhf(acc[i][0]+bj[0]); o0.y = tanhf(acc[i][1]+bj[1]);
      o0.z = tanhf(acc[i][2]+bj[2]); o0.w = tanhf(acc[i][3]+bj[3]);
      o1.x = tanhf(acc[i][4]+bj[4]); o1.y = tanhf(acc[i][5]+bj[5]);
      o1.z = tanhf(acc[i][6]+bj[6]); o1.w = tanhf(acc[i][7]+bj[7]);
      ((float4*)crow)[0] = o0; ((float4*)crow)[1] = o1;
    }
  }
}

// -------- in-place LayerNorm per 512-chunk (3 gates) + gain/bias fold -------
template<typename XT>
__global__ __launch_bounds__(256)
void ln3_kernel(XT* __restrict__ xp, const float* __restrict__ g,
                const float* __restrict__ be, const float* __restrict__ b)
{
  const size_t base = (size_t)blockIdx.x * G3_;
  const int t = threadIdx.x;
  float v[6];
  #pragma unroll
  for (int gg = 0; gg < 3; ++gg) {
    v[gg*2+0] = toF(xp[base + gg*512 + t]);
    v[gg*2+1] = toF(xp[base + gg*512 + 256 + t]);
  }
  float s0 = v[0]+v[1], q0 = v[0]*v[0]+v[1]*v[1];
  float s1 = v[2]+v[3], q1 = v[2]*v[2]+v[3]*v[3];
  float s2 = v[4]+v[5], q2 = v[4]*v[4]+v[5]*v[5];
  #pragma unroll
  for (int m = 1; m < 64; m <<= 1) {
    s0 += __shfl_xor(s0, m); q0 += __shfl_xor(q0, m);
    s1 += __shfl_xor(s1, m); q1 += __shfl_xor(q1, m);
    s2 += __shfl_xor(s2, m); q2 += __shfl_xor(q2, m);
  }
  __shared__ float red[4][6];
  __shared__ float stat[6];
  const int wid = t >> 6, lane = t & 63;
  if (lane == 0) { red[wid][0]=s0; red[wid][1]=q0; red[wid][2]=s1; red[wid][3]=q1; red[wid][4]=s2; red[wid][5]=q2; }
  __syncthreads();
  if (t < 6) stat[t] = red[0][t] + red[1][t] + red[2][t] + red[3][t];
  __syncthreads();
  #pragma unroll
  for (int gg = 0; gg < 3; ++gg) {
    const float mu  = stat[gg*2]   * (1.f/512.f);
    const float var = stat[gg*2+1] * (1.f/512.f) - mu*mu;
    const float sc  = rsqrtf(var + 1e-5f);
    #pragma unroll
    for (int u = 0; u < 2; ++u) {
      const int c = gg*512 + u*256 + t;
      storeF(&xp[base + c], (v[gg*2+u] - mu) * sc * g[c] + be[c] + b[c]);
    }
  }
}

// --------------------------- persistent scan kernel -------------------------
// Geometry: group = 8 batches; 8 groups/dir; 32 j-slice blocks per group.
// Round-6 proven sync protocol: per-block step-stamped FLAGS, each in its own
// 128B line (relaxed agent store; no RMW, no shared lines); bulk data via
// relaxed agent-scope loads/stores (L3-coherent, read ONCE after flag);
// s_waitcnt vmcnt(0)+__syncthreads before each flag publish.
// Parallel launch: grid 512 covers both dirs (2 blocks/CU; the two dirs'
// stalls overlap). Sequential launch: grid 256, dirbase selects dir.
template<typename XT, typename HT>
__global__ __launch_bounds__(256, 2)
void scan_kernel(const XT* __restrict__ xp_f, const XT* __restrict__ xp_b,
                 const float* __restrict__ Whh_f, const float* __restrict__ Whh_b,
                 const float* __restrict__ gf, const float* __restrict__ bef, const float* __restrict__ bfv,
                 const float* __restrict__ gbv, const float* __restrict__ beb, const float* __restrict__ bbv,
                 float* __restrict__ hbuf, float* __restrict__ part,
                 unsigned* __restrict__ flags,
                 HT* __restrict__ houtF, int rsF, XT* __restrict__ houtB, int rsB,
                 float* __restrict__ outhid, int dirbase)
{
  __shared__ float hT[8][512];
  __shared__ float red[4][16][26];
  __shared__ float statL[48];
  __shared__ int sdead;

  const int bid  = blockIdx.x;
  const int gidx = dirbase*8 + (bid >> 5);   // global group 0..15
  const int dir  = gidx >> 3;
  const int bg   = gidx & 7;                 // batch group (8 batches)
  const int js   = bid & 31;                 // j slice
  const int tid  = threadIdx.x;
  const int jloc = tid & 15;
  const int pb   = tid >> 4;                 // dots: k-slice id; gates: b id
  const int wid  = tid >> 6;
  const int ksw  = (tid >> 4) & 3;
  const int j    = js*16 + jloc;

  const XT* xp   = dir ? xp_b : xp_f;
  const float* W = dir ? Whh_b : Whh_f;
  const float* gv  = dir ? gbv : gf;
  const float* bev = dir ? beb : bef;
  const float* bv  = dir ? bbv : bfv;
  float* h = hbuf + dir * (B_ * H_);
  float* pgrp = part + (size_t)gidx * (48*32);
  unsigned* hfl = flags + (size_t)gidx * 2048;   // 32 x 128B lines
  unsigned* sfl = hfl + 1024;                     // 32 x 128B lines

  if (tid == 0) sdead = 0;

  // W slice in registers; chunk order permuted by ksw (bank-conflict spread)
  float w[3][32];
  {
    #pragma unroll
    for (int r = 0; r < 3; ++r) {
      const float* wr = W + (size_t)(r*H_ + j) * H_ + pb * 32;
      #pragma unroll
      for (int c = 0; c < 8; ++c) {
        const int p = (c + ksw*2) & 7;
        float4 f = *(const float4*)(wr + p*4);
        w[r][c*4+0] = f.x; w[r][c*4+1] = f.y; w[r][c*4+2] = f.z; w[r][c*4+3] = f.w;
      }
    }
  }
  const float gr0 = gv[j],            gr1 = gv[H_+j],               gr2 = gv[2*H_+j];
  const float gb0 = bev[j] + bv[j],   gb1 = bev[H_+j] + bv[H_+j],   gb2 = bev[2*H_+j] + bv[2*H_+j];
  __syncthreads();   // sdead visible

  for (int t = 0; t < S_; ++t) {
    // prefetch xp gate inputs (independent of h -> overlaps the flag poll)
    const int tf = dir ? (S_ - 1 - t) : t;
    float xr = 0.f, xz = 0.f, xn = 0.f;
    if (pb < 8) {
      const size_t xbase = ((size_t)tf * B_ + bg*8 + pb) * G3_;
      xr = toF(xp[xbase + j]);
      xz = toF(xp[xbase + H_ + j]);
      xn = toF(xp[xbase + 2*H_ + j]);
    }

    // ---- barrier 1: h(t-1) published by all 32 blocks ----
    if (tid < 32 && !sdead) {
      const unsigned tgt = (unsigned)t;
      int guard = 0;
      while (flagLoad(&hfl[tid*32]) < tgt) {
        __builtin_amdgcn_s_sleep(1);
        if (++guard > (1 << 22)) { sdead = 1; break; }
      }
    }
    __syncthreads();

    // stage h tile (8 b x 512 f32): coalesced 8B coherent loads, once
    {
      const int row = tid >> 5;          // 0..7
      const int seg = tid & 31;
      const ULL* hr = (const ULL*)(h + (size_t)(bg*8 + row) * H_);
      ULL v[8];
      #pragma unroll
      for (int i = 0; i < 8; ++i) v[i] = cohLoad8(hr + seg + i*32);
      ULL* dst = (ULL*)&hT[row][0];
      #pragma unroll
      for (int i = 0; i < 8; ++i) dst[seg + i*32] = v[i];
    }
    __syncthreads();

    // k-sliced dots for the 8 b of this group
    for (int b = 0; b < 8; ++b) {
      float a0 = 0.f, a1 = 0.f, a2 = 0.f;
      #pragma unroll
      for (int c = 0; c < 8; ++c) {
        const int p = (c + ksw*2) & 7;
        const float4 hv = *(const float4*)&hT[b][pb*32 + p*4];
        a0 += hv.x*w[0][c*4+0] + hv.y*w[0][c*4+1] + hv.z*w[0][c*4+2] + hv.w*w[0][c*4+3];
        a1 += hv.x*w[1][c*4+0] + hv.y*w[1][c*4+1] + hv.z*w[1][c*4+2] + hv.w*w[1][c*4+3];
        a2 += hv.x*w[2][c*4+0] + hv.y*w[2][c*4+1] + hv.z*w[2][c*4+2] + hv.w*w[2][c*4+3];
      }
      a0 += __shfl_xor(a0, 16); a0 += __shfl_xor(a0, 32);
      a1 += __shfl_xor(a1, 16); a1 += __shfl_xor(a1, 32);
      a2 += __shfl_xor(a2, 16); a2 += __shfl_xor(a2, 32);
      if (ksw == 0) {
        red[wid][jloc][b*3+0] = a0; red[wid][jloc][b*3+1] = a1; red[wid][jloc][b*3+2] = a2;
      }
    }
    __syncthreads();

    float vr = 0.f, vz = 0.f, vn = 0.f;
    if (pb < 8) {
      vr = red[0][jloc][pb*3+0]+red[1][jloc][pb*3+0]+red[2][jloc][pb*3+0]+red[3][jloc][pb*3+0];
      vz = red[0][jloc][pb*3+1]+red[1][jloc][pb*3+1]+red[2][jloc][pb*3+1]+red[3][jloc][pb*3+1];
      vn = red[0][jloc][pb*3+2]+red[1][jloc][pb*3+2]+red[2][jloc][pb*3+2]+red[3][jloc][pb*3+2];

      // LN-stat partials over this block's 16 j -> group buffer [48][32]
      float sr = vr, qr = vr*vr, sz = vz, qz = vz*vz, sn = vn, qn = vn*vn;
      #pragma unroll
      for (int m = 1; m < 16; m <<= 1) {
        sr += __shfl_xor(sr, m); qr += __shfl_xor(qr, m);
        sz += __shfl_xor(sz, m); qz += __shfl_xor(qz, m);
        sn += __shfl_xor(sn, m); qn += __shfl_xor(qn, m);
      }
      if (jloc == 0) {
        cohStore4(&pgrp[(pb*6+0)*32 + js], sr);
        cohStore4(&pgrp[(pb*6+1)*32 + js], qr);
        cohStore4(&pgrp[(pb*6+2)*32 + js], sz);
        cohStore4(&pgrp[(pb*6+3)*32 + js], qz);
        cohStore4(&pgrp[(pb*6+4)*32 + js], sn);
        cohStore4(&pgrp[(pb*6+5)*32 + js], qn);
      }
    }
    asm volatile("s_waitcnt vmcnt(0)" ::: "memory");
    __syncthreads();

    // ---- barrier 2: all 32 blocks' partials at L3 ----
    if (tid == 0) flagStore(&sfl[js*32], (unsigned)(t + 1));
    if (tid < 32 && !sdead) {
      const unsigned tgt = (unsigned)(t + 1);
      int guard = 0;
      while (flagLoad(&sfl[tid*32]) < tgt) {
        __builtin_amdgcn_s_sleep(1);
        if (++guard > (1 << 22)) { sdead = 1; break; }
      }
    }
    __syncthreads();

    // reduce 32 slot-partials -> LN stats (8 b x 3 gates x {sum, sumsq})
    if (tid < 48) {
      const ULL* prow = (const ULL*)(pgrp + tid * 32);
      float s = 0.f;
      #pragma unroll
      for (int u = 0; u < 16; ++u) {
        ULL v = cohLoad8(prow + u);
        union { ULL u64; float f[2]; } cv; cv.u64 = v;
        s += cv.f[0] + cv.f[1];
      }
      statL[tid] = s;
    }
    __syncthreads();

    // gates + h update (thread owns (b=pb<8, j))
    if (pb < 8) {
      const int ab = bg*8 + pb;
      const float mur   = statL[pb*6+0]*(1.f/512.f);
      const float var_r = statL[pb*6+1]*(1.f/512.f) - mur*mur;
      const float muz   = statL[pb*6+2]*(1.f/512.f);
      const float var_z = statL[pb*6+3]*(1.f/512.f) - muz*muz;
      const float mun   = statL[pb*6+4]*(1.f/512.f);
      const float var_n = statL[pb*6+5]*(1.f/512.f) - mun*mun;
      const float hr_ = (vr - mur) * rsqrtf(var_r + 1e-5f) * gr0 + gb0;
      const float hz_ = (vz - muz) * rsqrtf(var_z + 1e-5f) * gr1 + gb1;
      const float hn_ = (vn - mun) * rsqrtf(var_n + 1e-5f) * gr2 + gb2;
      const float rg = 1.f / (1.f + __expf(-(xr + hr_)));
      const float zg = 1.f / (1.f + __expf(-(xz + hz_)));
      const float ng = tanhf(xn + rg * hn_);
      const float hprev = hT[pb][j];
      const float hnew = (1.f - zg) * ng + zg * hprev;
      cohStore4(&h[(size_t)ab * H_ + j], hnew);
      if (dir == 0) storeF(&houtF[((size_t)tf * B_ + ab) * rsF + j], hnew);
      else          storeF(&houtB[((size_t)tf * B_ + ab) * rsB + j], hnew);
      if (t == S_ - 1) outhid[((size_t)dir * B_ + ab) * H_ + j] = hnew;
    }
    asm volatile("s_waitcnt vmcnt(0)" ::: "memory");
    __syncthreads();
    if (tid == 0) flagStore(&hfl[js*32], (unsigned)(t + 1));
  }
}

// --------------------------------- host side --------------------------------
// ctrl: hbuf 256KB | part 96KB | flags 128KB | pad -> 512KB
static const size_t kCtrlBytes = 524288;
static const size_t kXpElems = (size_t)S_ * B_ * G3_;   // 100,663,296
static const size_t kHElems  = (size_t)S_ * B_ * H_;    //  33,554,432

struct Args {
  const int* src; const float* emb;
  const float *Wih_f, *Whh_f, *bih_f, *bhh_f, *gih_f, *beih_f, *ghh_f, *behh_f;
  const float *Wih_b, *Whh_b, *bih_b, *bhh_b, *gih_b, *beih_b, *ghh_b, *behh_b;
  const float *Wout, *bout;
  float* out; void* ws; hipStream_t stream;
};

// parallel: both directions concurrent (grid 512, 2 blocks/CU); xp fp16;
// h-histories alias into dead xp cols 0..511.
template<typename XT>
static void run_parallel(const Args& a)
{
  float* hbuf = (float*)a.ws;
  float* part = hbuf + 65536;
  unsigned* flags = (unsigned*)(part + 24576);
  XT* xpf = (XT*)((char*)a.ws + kCtrlBytes);
  XT* xpb = xpf + kXpElems;
  float* outhid = a.out + kHElems;

  hipMemsetAsync(a.ws, 0, kCtrlBytes, a.stream);

  gemm_tile<XT,XT,0,0><<<dim3(512,12), dim3(256), 0, a.stream>>>(
      a.src, a.emb, (const XT*)nullptr, 0, (const XT*)nullptr, 0,
      a.Wih_f, xpf, nullptr, nullptr, G3_, E_);
  gemm_tile<XT,XT,0,0><<<dim3(512,12), dim3(256), 0, a.stream>>>(
      a.src, a.emb, (const XT*)nullptr, 0, (const XT*)nullptr, 0,
      a.Wih_b, xpb, nullptr, nullptr, G3_, E_);
  ln3_kernel<XT><<<dim3(S_*B_), dim3(256), 0, a.stream>>>(xpf, a.gih_f, a.beih_f, a.bih_f);
  ln3_kernel<XT><<<dim3(S_*B_), dim3(256), 0, a.stream>>>(xpb, a.gih_b, a.beih_b, a.bih_b);

  scan_kernel<XT,XT><<<dim3(512), dim3(256), 0, a.stream>>>(
      xpf, xpb, a.Whh_f, a.Whh_b, a.ghh_f, a.behh_f, a.bhh_f,
      a.ghh_b, a.behh_b, a.bhh_b, hbuf, part, flags,
      xpf, G3_, xpb, G3_, outhid, 0);

  gemm_tile<XT,XT,1,1><<<dim3(512,4), dim3(256), 0, a.stream>>>(
      nullptr, nullptr, xpf, G3_, xpb, G3_,
      a.Wout, (XT*)nullptr, a.out, a.bout, H_, 2*H_);
}

// sequential fallback: one xp buffer reused; yf -> hf, yb -> xp cols 0..511.
template<typename XT, typename HT>
static void run_sequential(const Args& a)
{
  float* hbuf = (float*)a.ws;
  float* part = hbuf + 65536;
  unsigned* flags = (unsigned*)(part + 24576);
  XT* xp = (XT*)((char*)a.ws + kCtrlBytes);
  HT* hf = (HT*)(xp + kXpElems);
  float* outhid = a.out + kHElems;

  hipMemsetAsync(a.ws, 0, kCtrlBytes, a.stream);

  gemm_tile<XT,XT,0,0><<<dim3(512,12), dim3(256), 0, a.stream>>>(
      a.src, a.emb, (const XT*)nullptr, 0, (const XT*)nullptr, 0,
      a.Wih_f, xp, nullptr, nullptr, G3_, E_);
  ln3_kernel<XT><<<dim3(S_*B_), dim3(256), 0, a.stream>>>(xp, a.gih_f, a.beih_f, a.bih_f);
  scan_kernel<XT,HT><<<dim3(256), dim3(256), 0, a.stream>>>(
      xp, xp, a.Whh_f, a.Whh_b, a.ghh_f, a.behh_f, a.bhh_f,
      a.ghh_b, a.behh_b, a.bhh_b, hbuf, part, flags,
      hf, H_, xp, G3_, outhid, 0);

  gemm_tile<XT,XT,0,0><<<dim3(512,12), dim3(256), 0, a.stream>>>(
      a.src, a.emb, (const XT*)nullptr, 0, (const XT*)nullptr, 0,
      a.Wih_b, xp, nullptr, nullptr, G3_, E_);
  ln3_kernel<XT><<<dim3(S_*B_), dim3(256), 0, a.stream>>>(xp, a.gih_b, a.beih_b, a.bih_b);
  scan_kernel<XT,HT><<<dim3(256), dim3(256), 0, a.stream>>>(
      xp, xp, a.Whh_f, a.Whh_b, a.ghh_f, a.behh_f, a.bhh_f,
      a.ghh_b, a.behh_b, a.bhh_b, hbuf, part, flags,
      hf, H_, xp, G3_, outhid, 1);

  gemm_tile<XT,HT,1,1><<<dim3(512,4), dim3(256), 0, a.stream>>>(
      nullptr, nullptr, hf, H_, xp, G3_,
      a.Wout, (XT*)nullptr, a.out, a.bout, H_, 2*H_);
}

extern "C" void kernel_launch(void* const* d_in, const int* in_sizes, int n_in,
                              void* d_out, int out_size, void* d_ws, size_t ws_size,
                              hipStream_t stream)
{
  Args a;
  a.src    = (const int*)  d_in[0];
  a.emb    = (const float*)d_in[1];
  a.Wih_f  = (const float*)d_in[2];
  a.Whh_f  = (const float*)d_in[3];
  a.bih_f  = (const float*)d_in[4];
  a.bhh_f  = (const float*)d_in[5];
  a.gih_f  = (const float*)d_in[6];
  a.beih_f = (const float*)d_in[7];
  a.ghh_f  = (const float*)d_in[8];
  a.behh_f = (const float*)d_in[9];
  a.Wih_b  = (const float*)d_in[10];
  a.Whh_b  = (const float*)d_in[11];
  a.bih_b  = (const float*)d_in[12];
  a.bhh_b  = (const float*)d_in[13];
  a.gih_b  = (const float*)d_in[14];
  a.beih_b = (const float*)d_in[15];
  a.ghh_b  = (const float*)d_in[16];
  a.behh_b = (const float*)d_in[17];
  a.Wout   = (const float*)d_in[18];
  a.bout   = (const float*)d_in[19];
  a.out = (float*)d_out;
  a.ws = d_ws;
  a.stream = stream;

  int dev = 0, cus = 0;
  hipGetDevice(&dev);
  hipDeviceGetAttribute(&cus, hipDeviceAttributeMultiprocessorCount, dev);

  const size_t needP = kCtrlBytes + 2*kXpElems*2;            // ~403.2 MB fp16 parallel
  const size_t needS = kCtrlBytes + kXpElems*2 + kHElems*2;  // ~269.0 MB fp16 sequential

  const bool sane = (n_in == 20) && (in_sizes[0] == S_*B_) && (in_sizes[1] == 32000*E_)
                 && (in_sizes[3] == G3_*H_) && (in_sizes[18] == H_*2*H_);

  float sigv = 0.f;
  bool ran = false;
  if (!sane) {
    sigv = 20000.f + (float)n_in;
  } else if (cus < 256) {
    sigv = 100000.f + (float)cus;
  } else if (ws_size >= needP) { run_parallel<f16>(a);        ran = true; }
  else if (ws_size >= needS) { run_sequential<f16,f16>(a);    ran = true; }
  else {
    unsigned wsMB = (unsigned)(ws_size >> 20);
    if (wsMB > 998) wsMB = 998;
    sigv = 1000.f + (float)wsMB;
  }

  if (!ran) {
    signal_kernel<<<dim3(1024), dim3(256), 0, stream>>>(a.out, (long)out_size, sigv);
  } else {
    hipError_t e = hipGetLastError();
    if (e != hipSuccess) {
      signal_kernel<<<dim3(1024), dim3(256), 0, stream>>>(a.out, (long)out_size,
                                                          10000.f + (float)(int)e);
    }
  }
}

// Round 9
// 10833.030 us; speedup vs baseline: 1.9996x; 1.2310x over previous
//
#include <hip/hip_runtime.h>
#include <hip/hip_bf16.h>
#include <hip/hip_fp16.h>

#define S_ 1024
#define B_ 64
#define E_ 512
#define H_ 512
#define G3_ 1536
#define V_ 32000

typedef __hip_bfloat16 bf16;
typedef __half f16;
typedef unsigned long long ULL;

typedef _Float16 half8 __attribute__((ext_vector_type(8)));
typedef float f32x4v __attribute__((ext_vector_type(4)));

// ---------- dtype helpers ----------
template<typename T> struct alignas(4*sizeof(T)) V4 { T v[4]; };

__device__ __forceinline__ float toF(float x){ return x; }
__device__ __forceinline__ float toF(bf16 x){ return __bfloat162float(x); }
__device__ __forceinline__ float toF(f16 x){ return __half2float(x); }
__device__ __forceinline__ void storeF(float* p, float v){ *p = v; }
__device__ __forceinline__ void storeF(bf16* p, float v){ *p = __float2bfloat16(v); }
__device__ __forceinline__ void storeF(f16* p, float v){ *p = __float2half(v); }

__device__ __forceinline__ ULL cohLoad8(const ULL* p){
  return __hip_atomic_load(p, __ATOMIC_RELAXED, __HIP_MEMORY_SCOPE_AGENT);
}
__device__ __forceinline__ void cohStore4(float* p, float v){
  __hip_atomic_store(p, v, __ATOMIC_RELAXED, __HIP_MEMORY_SCOPE_AGENT);
}
__device__ __forceinline__ unsigned flagLoad(const unsigned* p){
  return __hip_atomic_load(p, __ATOMIC_RELAXED, __HIP_MEMORY_SCOPE_AGENT);
}
__device__ __forceinline__ void flagStore(unsigned* p, unsigned v){
  __hip_atomic_store(p, v, __ATOMIC_RELAXED, __HIP_MEMORY_SCOPE_AGENT);
}

// ------------------------------ signal kernel -------------------------------
__global__ __launch_bounds__(256)
void signal_kernel(float* __restrict__ out, long n, float v)
{
  long i = (long)blockIdx.x * 256 + threadIdx.x;
  const long stride = (long)gridDim.x * 256;
  for (; i < n; i += stride) out[i] = v;
}

// ---------------------------- fp32 -> fp16 convert --------------------------
__global__ __launch_bounds__(256)
void convF2H(const float* __restrict__ in, f16* __restrict__ out, long n)
{
  long i = ((long)blockIdx.x * 256 + threadIdx.x) * 8;
  const long stride = (long)gridDim.x * 256 * 8;
  for (; i < n; i += stride) {
    float4 a = *(const float4*)(in + i);
    float4 b = *(const float4*)(in + i + 4);
    half8 o;
    o[0] = (_Float16)a.x; o[1] = (_Float16)a.y; o[2] = (_Float16)a.z; o[3] = (_Float16)a.w;
    o[4] = (_Float16)b.x; o[5] = (_Float16)b.y; o[6] = (_Float16)b.z; o[7] = (_Float16)b.w;
    *(half8*)((_Float16*)out + i) = o;
  }
}

// ------------------------- MFMA fp16 GEMM (no LDS) ---------------------------
// C[m][n] = sum_k A[m][k] * W[n][k], A/W fp16, fp32 accumulate.
// Block 128x128, 4 waves (2x2), wave tile 64x64 = 4x4 MFMA 16x16x32 tiles.
// A/B fragments: lane l loads 8 contiguous fp16 at k = k0 + (l>>4)*8 from
// row (l&15) of its sub-tile. Same per-lane k-slot bijection for A and B =>
// layout-correct independent of the HW k-group map. C/D: col=l&15,
// row=(l>>4)*4+reg [HW-verified].
// GMODE 0: A row = emb16[src[m]] * (src!=0)    (gather, K=512)
// GMODE 1: A[m][k] = k<512 ? Af[m*rsF+k] : Ab[m*rsB+k-512]
// EPI 0: store f16 to Cx (row stride N). EPI 1: f32 tanh(acc+bias[n]) to Cf.
template<int GMODE, int EPI>
__global__ __launch_bounds__(256)
void gemm16(const int* __restrict__ src, const f16* __restrict__ embh,
            const f16* __restrict__ Af, int rsF,
            const f16* __restrict__ Ab, int rsB,
            const f16* __restrict__ Wh,
            f16* __restrict__ Cx, float* __restrict__ Cf,
            const float* __restrict__ bias, int N, int K)
{
  __shared__ int s_tok[128];
  const int tid = threadIdx.x;
  const int m0 = blockIdx.x * 128;
  const int n0 = blockIdx.y * 128;
  const int wid = tid >> 6, lane = tid & 63;
  const int wr = wid >> 1, wc = wid & 1;
  const int lr = lane & 15, lg = lane >> 4;

  if constexpr (GMODE == 0) {
    if (tid < 128) s_tok[tid] = src[m0 + tid];
  }
  __syncthreads();

  f32x4v acc[4][4];
  #pragma unroll
  for (int i = 0; i < 4; ++i)
    #pragma unroll
    for (int j = 0; j < 4; ++j) {
      acc[i][j][0] = 0.f; acc[i][j][1] = 0.f; acc[i][j][2] = 0.f; acc[i][j][3] = 0.f;
    }

  int atok[4]; size_t abase[4];
  #pragma unroll
  for (int i = 0; i < 4; ++i) {
    const int lm = wr*64 + i*16 + lr;
    if constexpr (GMODE == 0) {
      const int tok = s_tok[lm];
      atok[i] = tok;
      abase[i] = (size_t)tok * K;
    } else {
      atok[i] = m0 + lm;
      abase[i] = 0;
    }
  }
  const half8 zero8 = {};

  for (int k0 = 0; k0 < K; k0 += 32) {
    const int kk = k0 + lg*8;
    half8 afr[4], bfr[4];
    #pragma unroll
    for (int i = 0; i < 4; ++i) {
      if constexpr (GMODE == 0) {
        afr[i] = *(const half8*)((const _Float16*)embh + abase[i] + kk);
        if (atok[i] == 0) afr[i] = zero8;
      } else {
        const int m = atok[i];
        const _Float16* p = (kk < 512)
            ? ((const _Float16*)Af + (size_t)m * rsF + kk)
            : ((const _Float16*)Ab + (size_t)m * rsB + (kk - 512));
        afr[i] = *(const half8*)p;
      }
    }
    #pragma unroll
    for (int j = 0; j < 4; ++j) {
      const int n = n0 + wc*64 + j*16 + lr;
      bfr[j] = *(const half8*)((const _Float16*)Wh + (size_t)n * K + kk);
    }
    #pragma unroll
    for (int i = 0; i < 4; ++i)
      #pragma unroll
      for (int j = 0; j < 4; ++j)
        acc[i][j] = __builtin_amdgcn_mfma_f32_16x16x32_f16(afr[i], bfr[j], acc[i][j], 0, 0, 0);
  }

  if constexpr (EPI == 0) {
    #pragma unroll
    for (int i = 0; i < 4; ++i) {
      #pragma unroll
      for (int j = 0; j < 4; ++j) {
        const int n = n0 + wc*64 + j*16 + lr;
        #pragma unroll
        for (int r = 0; r < 4; ++r) {
          const int m = m0 + wr*64 + i*16 + lg*4 + r;
          Cx[(size_t)m * N + n] = __float2half(acc[i][j][r]);
        }
      }
    }
  } else {
    #pragma unroll
    for (int j = 0; j < 4; ++j) {
      const int n = n0 + wc*64 + j*16 + lr;
      const float bj = bias[n];
      #pragma unroll
      for (int i = 0; i < 4; ++i) {
        #pragma unroll
        for (int r = 0; r < 4; ++r) {
          const int m = m0 + wr*64 + i*16 + lg*4 + r;
          Cf[(size_t)m * N + n] = tanhf(acc[i][j][r] + bj);
        }
      }
    }
  }
}

// -------- in-place LayerNorm per 512-chunk (3 gates) + gain/bias fold -------
template<typename XT>
__global__ __launch_bounds__(256)
void ln3_kernel(XT* __restrict__ xp, const float* __restrict__ g,
                const float* __restrict__ be, const float* __restrict__ b)
{
  const size_t base = (size_t)blockIdx.x * G3_;
  const int t = threadIdx.x;
  float v[6];
  #pragma unroll
  for (int gg = 0; gg < 3; ++gg) {
    v[gg*2+0] = toF(xp[base + gg*512 + t]);
    v[gg*2+1] = toF(xp[base + gg*512 + 256 + t]);
  }
  float s0 = v[0]+v[1], q0 = v[0]*v[0]+v[1]*v[1];
  float s1 = v[2]+v[3], q1 = v[2]*v[2]+v[3]*v[3];
  float s2 = v[4]+v[5], q2 = v[4]*v[4]+v[5]*v[5];
  #pragma unroll
  for (int m = 1; m < 64; m <<= 1) {
    s0 += __shfl_xor(s0, m); q0 += __shfl_xor(q0, m);
    s1 += __shfl_xor(s1, m); q1 += __shfl_xor(q1, m);
    s2 += __shfl_xor(s2, m); q2 += __shfl_xor(q2, m);
  }
  __shared__ float red[4][6];
  __shared__ float stat[6];
  const int wid = t >> 6, lane = t & 63;
  if (lane == 0) { red[wid][0]=s0; red[wid][1]=q0; red[wid][2]=s1; red[wid][3]=q1; red[wid][4]=s2; red[wid][5]=q2; }
  __syncthreads();
  if (t < 6) stat[t] = red[0][t] + red[1][t] + red[2][t] + red[3][t];
  __syncthreads();
  #pragma unroll
  for (int gg = 0; gg < 3; ++gg) {
    const float mu  = stat[gg*2]   * (1.f/512.f);
    const float var = stat[gg*2+1] * (1.f/512.f) - mu*mu;
    const float sc  = rsqrtf(var + 1e-5f);
    #pragma unroll
    for (int u = 0; u < 2; ++u) {
      const int c = gg*512 + u*256 + t;
      storeF(&xp[base + c], (v[gg*2+u] - mu) * sc * g[c] + be[c] + b[c]);
    }
  }
}

// --------------------------- persistent scan kernel -------------------------
// (unchanged from round 8 — measured-best sync protocol)
template<typename XT, typename HT>
__global__ __launch_bounds__(256, 2)
void scan_kernel(const XT* __restrict__ xp_f, const XT* __restrict__ xp_b,
                 const float* __restrict__ Whh_f, const float* __restrict__ Whh_b,
                 const float* __restrict__ gf, const float* __restrict__ bef, const float* __restrict__ bfv,
                 const float* __restrict__ gbv, const float* __restrict__ beb, const float* __restrict__ bbv,
                 float* __restrict__ hbuf, float* __restrict__ part,
                 unsigned* __restrict__ flags,
                 HT* __restrict__ houtF, int rsF, XT* __restrict__ houtB, int rsB,
                 float* __restrict__ outhid, int dirbase)
{
  __shared__ float hT[8][512];
  __shared__ float red[4][16][26];
  __shared__ float statL[48];
  __shared__ int sdead;

  const int bid  = blockIdx.x;
  const int gidx = dirbase*8 + (bid >> 5);
  const int dir  = gidx >> 3;
  const int bg   = gidx & 7;
  const int js   = bid & 31;
  const int tid  = threadIdx.x;
  const int jloc = tid & 15;
  const int pb   = tid >> 4;
  const int wid  = tid >> 6;
  const int ksw  = (tid >> 4) & 3;
  const int j    = js*16 + jloc;

  const XT* xp   = dir ? xp_b : xp_f;
  const float* W = dir ? Whh_b : Whh_f;
  const float* gv  = dir ? gbv : gf;
  const float* bev = dir ? beb : bef;
  const float* bv  = dir ? bbv : bfv;
  float* h = hbuf + dir * (B_ * H_);
  float* pgrp = part + (size_t)gidx * (48*32);
  unsigned* hfl = flags + (size_t)gidx * 2048;
  unsigned* sfl = hfl + 1024;

  if (tid == 0) sdead = 0;

  float w[3][32];
  {
    #pragma unroll
    for (int r = 0; r < 3; ++r) {
      const float* wr = W + (size_t)(r*H_ + j) * H_ + pb * 32;
      #pragma unroll
      for (int c = 0; c < 8; ++c) {
        const int p = (c + ksw*2) & 7;
        float4 f = *(const float4*)(wr + p*4);
        w[r][c*4+0] = f.x; w[r][c*4+1] = f.y; w[r][c*4+2] = f.z; w[r][c*4+3] = f.w;
      }
    }
  }
  const float gr0 = gv[j],            gr1 = gv[H_+j],               gr2 = gv[2*H_+j];
  const float gb0 = bev[j] + bv[j],   gb1 = bev[H_+j] + bv[H_+j],   gb2 = bev[2*H_+j] + bv[2*H_+j];
  __syncthreads();

  for (int t = 0; t < S_; ++t) {
    const int tf = dir ? (S_ - 1 - t) : t;
    float xr = 0.f, xz = 0.f, xn = 0.f;
    if (pb < 8) {
      const size_t xbase = ((size_t)tf * B_ + bg*8 + pb) * G3_;
      xr = toF(xp[xbase + j]);
      xz = toF(xp[xbase + H_ + j]);
      xn = toF(xp[xbase + 2*H_ + j]);
    }

    if (tid < 32 && !sdead) {
      const unsigned tgt = (unsigned)t;
      int guard = 0;
      while (flagLoad(&hfl[tid*32]) < tgt) {
        __builtin_amdgcn_s_sleep(1);
        if (++guard > (1 << 22)) { sdead = 1; break; }
      }
    }
    __syncthreads();

    {
      const int row = tid >> 5;
      const int seg = tid & 31;
      const ULL* hr = (const ULL*)(h + (size_t)(bg*8 + row) * H_);
      ULL v[8];
      #pragma unroll
      for (int i = 0; i < 8; ++i) v[i] = cohLoad8(hr + seg + i*32);
      ULL* dst = (ULL*)&hT[row][0];
      #pragma unroll
      for (int i = 0; i < 8; ++i) dst[seg + i*32] = v[i];
    }
    __syncthreads();

    for (int b = 0; b < 8; ++b) {
      float a0 = 0.f, a1 = 0.f, a2 = 0.f;
      #pragma unroll
      for (int c = 0; c < 8; ++c) {
        const int p = (c + ksw*2) & 7;
        const float4 hv = *(const float4*)&hT[b][pb*32 + p*4];
        a0 += hv.x*w[0][c*4+0] + hv.y*w[0][c*4+1] + hv.z*w[0][c*4+2] + hv.w*w[0][c*4+3];
        a1 += hv.x*w[1][c*4+0] + hv.y*w[1][c*4+1] + hv.z*w[1][c*4+2] + hv.w*w[1][c*4+3];
        a2 += hv.x*w[2][c*4+0] + hv.y*w[2][c*4+1] + hv.z*w[2][c*4+2] + hv.w*w[2][c*4+3];
      }
      a0 += __shfl_xor(a0, 16); a0 += __shfl_xor(a0, 32);
      a1 += __shfl_xor(a1, 16); a1 += __shfl_xor(a1, 32);
      a2 += __shfl_xor(a2, 16); a2 += __shfl_xor(a2, 32);
      if (ksw == 0) {
        red[wid][jloc][b*3+0] = a0; red[wid][jloc][b*3+1] = a1; red[wid][jloc][b*3+2] = a2;
      }
    }
    __syncthreads();

    float vr = 0.f, vz = 0.f, vn = 0.f;
    if (pb < 8) {
      vr = red[0][jloc][pb*3+0]+red[1][jloc][pb*3+0]+red[2][jloc][pb*3+0]+red[3][jloc][pb*3+0];
      vz = red[0][jloc][pb*3+1]+red[1][jloc][pb*3+1]+red[2][jloc][pb*3+1]+red[3][jloc][pb*3+1];
      vn = red[0][jloc][pb*3+2]+red[1][jloc][pb*3+2]+red[2][jloc][pb*3+2]+red[3][jloc][pb*3+2];

      float sr = vr, qr = vr*vr, sz = vz, qz = vz*vz, sn = vn, qn = vn*vn;
      #pragma unroll
      for (int m = 1; m < 16; m <<= 1) {
        sr += __shfl_xor(sr, m); qr += __shfl_xor(qr, m);
        sz += __shfl_xor(sz, m); qz += __shfl_xor(qz, m);
        sn += __shfl_xor(sn, m); qn += __shfl_xor(qn, m);
      }
      if (jloc == 0) {
        cohStore4(&pgrp[(pb*6+0)*32 + js], sr);
        cohStore4(&pgrp[(pb*6+1)*32 + js], qr);
        cohStore4(&pgrp[(pb*6+2)*32 + js], sz);
        cohStore4(&pgrp[(pb*6+3)*32 + js], qz);
        cohStore4(&pgrp[(pb*6+4)*32 + js], sn);
        cohStore4(&pgrp[(pb*6+5)*32 + js], qn);
      }
    }
    asm volatile("s_waitcnt vmcnt(0)" ::: "memory");
    __syncthreads();

    if (tid == 0) flagStore(&sfl[js*32], (unsigned)(t + 1));
    if (tid < 32 && !sdead) {
      const unsigned tgt = (unsigned)(t + 1);
      int guard = 0;
      while (flagLoad(&sfl[tid*32]) < tgt) {
        __builtin_amdgcn_s_sleep(1);
        if (++guard > (1 << 22)) { sdead = 1; break; }
      }
    }
    __syncthreads();

    if (tid < 48) {
      const ULL* prow = (const ULL*)(pgrp + tid * 32);
      float s = 0.f;
      #pragma unroll
      for (int u = 0; u < 16; ++u) {
        ULL v = cohLoad8(prow + u);
        union { ULL u64; float f[2]; } cv; cv.u64 = v;
        s += cv.f[0] + cv.f[1];
      }
      statL[tid] = s;
    }
    __syncthreads();

    if (pb < 8) {
      const int ab = bg*8 + pb;
      const float mur   = statL[pb*6+0]*(1.f/512.f);
      const float var_r = statL[pb*6+1]*(1.f/512.f) - mur*mur;
      const float muz   = statL[pb*6+2]*(1.f/512.f);
      const float var_z = statL[pb*6+3]*(1.f/512.f) - muz*muz;
      const float mun   = statL[pb*6+4]*(1.f/512.f);
      const float var_n = statL[pb*6+5]*(1.f/512.f) - mun*mun;
      const float hr_ = (vr - mur) * rsqrtf(var_r + 1e-5f) * gr0 + gb0;
      const float hz_ = (vz - muz) * rsqrtf(var_z + 1e-5f) * gr1 + gb1;
      const float hn_ = (vn - mun) * rsqrtf(var_n + 1e-5f) * gr2 + gb2;
      const float rg = 1.f / (1.f + __expf(-(xr + hr_)));
      const float zg = 1.f / (1.f + __expf(-(xz + hz_)));
      const float ng = tanhf(xn + rg * hn_);
      const float hprev = hT[pb][j];
      const float hnew = (1.f - zg) * ng + zg * hprev;
      cohStore4(&h[(size_t)ab * H_ + j], hnew);
      if (dir == 0) storeF(&houtF[((size_t)tf * B_ + ab) * rsF + j], hnew);
      else          storeF(&houtB[((size_t)tf * B_ + ab) * rsB + j], hnew);
      if (t == S_ - 1) outhid[((size_t)dir * B_ + ab) * H_ + j] = hnew;
    }
    asm volatile("s_waitcnt vmcnt(0)" ::: "memory");
    __syncthreads();
    if (tid == 0) flagStore(&hfl[js*32], (unsigned)(t + 1));
  }
}

// --------------------------------- host side --------------------------------
// ctrl: hbuf 256KB | part 96KB | flags 128KB | pad -> 512KB
static const size_t kCtrlBytes = 524288;
static const size_t kXpElems = (size_t)S_ * B_ * G3_;   // 100,663,296
static const size_t kHElems  = (size_t)S_ * B_ * H_;    //  33,554,432
static const size_t kEmbElems  = (size_t)V_ * E_;       //  16,384,000
static const size_t kWihElems  = (size_t)G3_ * E_;      //     786,432
static const size_t kWoutElems = (size_t)H_ * 2 * H_;   //     524,288

struct Args {
  const int* src; const float* emb;
  const float *Wih_f, *Whh_f, *bih_f, *bhh_f, *gih_f, *beih_f, *ghh_f, *behh_f;
  const float *Wih_b, *Whh_b, *bih_b, *bhh_b, *gih_b, *beih_b, *ghh_b, *behh_b;
  const float *Wout, *bout;
  float* out; void* ws; hipStream_t stream;
};

// parallel: both directions concurrent; all big intermediates fp16; MFMA GEMMs.
static void run_parallel(const Args& a)
{
  float* hbuf = (float*)a.ws;
  float* part = hbuf + 65536;
  unsigned* flags = (unsigned*)(part + 24576);
  f16* xpf = (f16*)((char*)a.ws + kCtrlBytes);
  f16* xpb = xpf + kXpElems;
  f16* emb16 = xpb + kXpElems;
  f16* w16f = emb16 + kEmbElems;
  f16* w16b = w16f + kWihElems;
  f16* wout16 = w16b + kWihElems;
  float* outhid = a.out + kHElems;

  hipMemsetAsync(a.ws, 0, kCtrlBytes, a.stream);

  convF2H<<<dim3(1024), dim3(256), 0, a.stream>>>(a.emb, emb16, (long)kEmbElems);
  convF2H<<<dim3(256), dim3(256), 0, a.stream>>>(a.Wih_f, w16f, (long)kWihElems);
  convF2H<<<dim3(256), dim3(256), 0, a.stream>>>(a.Wih_b, w16b, (long)kWihElems);
  convF2H<<<dim3(256), dim3(256), 0, a.stream>>>(a.Wout, wout16, (long)kWoutElems);

  gemm16<0,0><<<dim3(512,12), dim3(256), 0, a.stream>>>(
      a.src, emb16, (const f16*)nullptr, 0, (const f16*)nullptr, 0,
      w16f, xpf, nullptr, nullptr, G3_, E_);
  gemm16<0,0><<<dim3(512,12), dim3(256), 0, a.stream>>>(
      a.src, emb16, (const f16*)nullptr, 0, (const f16*)nullptr, 0,
      w16b, xpb, nullptr, nullptr, G3_, E_);
  ln3_kernel<f16><<<dim3(S_*B_), dim3(256), 0, a.stream>>>(xpf, a.gih_f, a.beih_f, a.bih_f);
  ln3_kernel<f16><<<dim3(S_*B_), dim3(256), 0, a.stream>>>(xpb, a.gih_b, a.beih_b, a.bih_b);

  scan_kernel<f16,f16><<<dim3(512), dim3(256), 0, a.stream>>>(
      xpf, xpb, a.Whh_f, a.Whh_b, a.ghh_f, a.behh_f, a.bhh_f,
      a.ghh_b, a.behh_b, a.bhh_b, hbuf, part, flags,
      xpf, G3_, xpb, G3_, outhid, 0);

  gemm16<1,1><<<dim3(512,4), dim3(256), 0, a.stream>>>(
      nullptr, nullptr, xpf, G3_, xpb, G3_,
      wout16, nullptr, a.out, a.bout, H_, 2*H_);
}

// sequential fallback (smaller ws): one xp buffer; yf -> hf, yb -> xp cols 0..511.
static void run_sequential(const Args& a)
{
  float* hbuf = (float*)a.ws;
  float* part = hbuf + 65536;
  unsigned* flags = (unsigned*)(part + 24576);
  f16* xp = (f16*)((char*)a.ws + kCtrlBytes);
  f16* hf = xp + kXpElems;
  f16* emb16 = hf + kHElems;
  f16* w16f = emb16 + kEmbElems;
  f16* w16b = w16f + kWihElems;
  f16* wout16 = w16b + kWihElems;
  float* outhid = a.out + kHElems;

  hipMemsetAsync(a.ws, 0, kCtrlBytes, a.stream);

  convF2H<<<dim3(1024), dim3(256), 0, a.stream>>>(a.emb, emb16, (long)kEmbElems);
  convF2H<<<dim3(256), dim3(256), 0, a.stream>>>(a.Wih_f, w16f, (long)kWihElems);
  convF2H<<<dim3(256), dim3(256), 0, a.stream>>>(a.Wih_b, w16b, (long)kWihElems);
  convF2H<<<dim3(256), dim3(256), 0, a.stream>>>(a.Wout, wout16, (long)kWoutElems);

  gemm16<0,0><<<dim3(512,12), dim3(256), 0, a.stream>>>(
      a.src, emb16, (const f16*)nullptr, 0, (const f16*)nullptr, 0,
      w16f, xp, nullptr, nullptr, G3_, E_);
  ln3_kernel<f16><<<dim3(S_*B_), dim3(256), 0, a.stream>>>(xp, a.gih_f, a.beih_f, a.bih_f);
  scan_kernel<f16,f16><<<dim3(256), dim3(256), 0, a.stream>>>(
      xp, xp, a.Whh_f, a.Whh_b, a.ghh_f, a.behh_f, a.bhh_f,
      a.ghh_b, a.behh_b, a.bhh_b, hbuf, part, flags,
      hf, H_, xp, G3_, outhid, 0);

  gemm16<0,0><<<dim3(512,12), dim3(256), 0, a.stream>>>(
      a.src, emb16, (const f16*)nullptr, 0, (const f16*)nullptr, 0,
      w16b, xp, nullptr, nullptr, G3_, E_);
  ln3_kernel<f16><<<dim3(S_*B_), dim3(256), 0, a.stream>>>(xp, a.gih_b, a.beih_b, a.bih_b);
  scan_kernel<f16,f16><<<dim3(256), dim3(256), 0, a.stream>>>(
      xp, xp, a.Whh_f, a.Whh_b, a.ghh_f, a.behh_f, a.bhh_f,
      a.ghh_b, a.behh_b, a.bhh_b, hbuf, part, flags,
      hf, H_, xp, G3_, outhid, 1);

  gemm16<1,1><<<dim3(512,4), dim3(256), 0, a.stream>>>(
      nullptr, nullptr, hf, H_, xp, G3_,
      wout16, nullptr, a.out, a.bout, H_, 2*H_);
}

extern "C" void kernel_launch(void* const* d_in, const int* in_sizes, int n_in,
                              void* d_out, int out_size, void* d_ws, size_t ws_size,
                              hipStream_t stream)
{
  Args a;
  a.src    = (const int*)  d_in[0];
  a.emb    = (const float*)d_in[1];
  a.Wih_f  = (const float*)d_in[2];
  a.Whh_f  = (const float*)d_in[3];
  a.bih_f  = (const float*)d_in[4];
  a.bhh_f  = (const float*)d_in[5];
  a.gih_f  = (const float*)d_in[6];
  a.beih_f = (const float*)d_in[7];
  a.ghh_f  = (const float*)d_in[8];
  a.behh_f = (const float*)d_in[9];
  a.Wih_b  = (const float*)d_in[10];
  a.Whh_b  = (const float*)d_in[11];
  a.bih_b  = (const float*)d_in[12];
  a.bhh_b  = (const float*)d_in[13];
  a.gih_b  = (const float*)d_in[14];
  a.beih_b = (const float*)d_in[15];
  a.ghh_b  = (const float*)d_in[16];
  a.behh_b = (const float*)d_in[17];
  a.Wout   = (const float*)d_in[18];
  a.bout   = (const float*)d_in[19];
  a.out = (float*)d_out;
  a.ws = d_ws;
  a.stream = stream;

  int dev = 0, cus = 0;
  hipGetDevice(&dev);
  hipDeviceGetAttribute(&cus, hipDeviceAttributeMultiprocessorCount, dev);

  const size_t extraElems = kEmbElems + 2*kWihElems + kWoutElems;
  const size_t needP = kCtrlBytes + (2*kXpElems + extraElems) * 2;          // ~420 MB
  const size_t needS = kCtrlBytes + (kXpElems + kHElems + extraElems) * 2;  // ~293 MB

  const bool sane = (n_in == 20) && (in_sizes[0] == S_*B_) && (in_sizes[1] == V_*E_)
                 && (in_sizes[3] == G3_*H_) && (in_sizes[18] == H_*2*H_);

  float sigv = 0.f;
  bool ran = false;
  if (!sane) {
    sigv = 20000.f + (float)n_in;
  } else if (cus < 256) {
    sigv = 100000.f + (float)cus;
  } else if (ws_size >= needP) { run_parallel(a);   ran = true; }
  else if (ws_size >= needS)   { run_sequential(a); ran = true; }
  else {
    unsigned wsMB = (unsigned)(ws_size >> 20);
    if (wsMB > 998) wsMB = 998;
    sigv = 1000.f + (float)wsMB;
  }

  if (!ran) {
    signal_kernel<<<dim3(1024), dim3(256), 0, stream>>>(a.out, (long)out_size, sigv);
  } else {
    hipError_t e = hipGetLastError();
    if (e != hipSuccess) {
      signal_kernel<<<dim3(1024), dim3(256), 0, stream>>>(a.out, (long)out_size,
                                                          10000.f + (float)(int)e);
    }
  }
}